// Round 8
// baseline (1095.432 us; speedup 1.0000x reference)
//
#include <hip/hip_runtime.h>
#include <math.h>

// B,C,T = 32,1024,1024; beta=0.95; thr=1.0; sigma=10.5
#define B_     32
#define C_     1024
#define T_     1024
#define RT     92                    // tap radius (|d|>92 cannot flip any f32 spike; validated r2-r7)
#define CT     64                    // channels per block
#define TT     64                    // time chunk
#define KC     8                     // channels per thread group
#define NTY    8                     // 8 waves, 512 threads
#define NJQ    48                    // 192 source cols / 4 per b128
#define WOFF   (RT + KC - 1)         // 99 center: tap idx = d + 99
#define NWT    200                   // tap floats (idx 0..198 real, 199 pad)
#define NWQ    50                    // 50 float4 tap registers
#define NCOLS  (CT + 2*RT)           // 248 staged channel columns
#define XSTR   252                   // xsT row stride (dwords): 16B-aligned
#define ISTR   68                    // I-strip row stride (dwords): conflict-free b128

// numpy-faithful f32 tap (identical op sequence; exp via correctly-rounded f64).
__device__ __forceinline__ float tap_value(float s, int d) {
    float u    = __fdiv_rn((float)d, s);
    float t1   = __fmul_rn(-0.5f, u);
    float t2   = __fmul_rn(t1, u);
    float e    = (float)exp((double)t2);
    float den  = __fmul_rn(s, sqrtf(6.2831854820251465f));
    float coef = __fdiv_rn(1.0f, den);
    return __fmul_rn(coef, e);
}

__global__ void init_w_kernel(const float* __restrict__ sigma, float* __restrict__ gw) {
    int i = threadIdx.x;
    if (i < NWT) {
        int d = i - WOFF;
        gw[i] = (d >= -RT && d <= RT) ? tap_value(sigma[0], d) : 0.0f;
    }
}

#define EL(v, i) ((i) == 0 ? (v).x : (i) == 1 ? (v).y : (i) == 2 ? (v).z : (v).w)

// xsT[t][chan_col] transposed tile -> conv reads ds_read_b128 along j.
// Taps: 50 float4 held in VGPRs for the entire kernel (loaded once) -> the
// conv inner loop has NO tap fetches, only 48 independent x-reads per chunk.
// Thread (tx,ty): channels c0+ty*8+k at t=t0+tx; wave-local I strip + scan.
template <bool GW>
__global__ __launch_bounds__(512, 4) void snn_v8(
    const float* __restrict__ x, const float* __restrict__ sigma,
    const float* __restrict__ gw, float* __restrict__ out)
{
    __shared__ __align__(16) float xsT[TT * XSTR];        // 64512 B
    __shared__ __align__(16) float IsS[NTY * KC * ISTR];  // 17408 B (total 81920)

    const int tx   = threadIdx.x;       // t lane 0..63
    const int ty   = threadIdx.y;       // wave 0..7
    const int flat = ty * 64 + tx;
    const int b    = blockIdx.y;
    const int c0   = blockIdx.x * CT;
    const int rb   = ty * KC;           // first local channel of this wave

    // ---- load all 200 taps into registers (once per kernel) ----
    float4 wq[NWQ];                     // statically indexed only (full unrolls)
    if (GW) {
        const float4* g4 = (const float4*)gw;
#pragma unroll
        for (int i = 0; i < NWQ; ++i) wq[i] = g4[i];
    } else {
        // fallback: compute taps into IsS, read back, then IsS is reused
        if (flat < NWT) {
            int d = flat - WOFF;
            IsS[flat] = (d >= -RT && d <= RT) ? tap_value(sigma[0], d) : 0.0f;
        }
        __syncthreads();
#pragma unroll
        for (int i = 0; i < NWQ; ++i) wq[i] = *(const float4*)(IsS + 4 * i);
        // first in-loop __syncthreads orders these reads vs strip writes
    }

    const float* xb = x   + (size_t)b * ((size_t)C_ * T_);
    float*       ob = out + (size_t)b * ((size_t)C_ * T_);

    // ---- register staging (T14): (r = chan col, c4 = t-quad) ----
    float4 stg[2][4];                   // statically indexed only
    const int rB  = (flat >> 2);        // 0..127
    const int c4B = (flat & 3);         // 0..3

#define STAGE_LOAD(T0)                                                          \
    _Pragma("unroll")                                                           \
    for (int i1 = 0; i1 < 2; ++i1) {                                            \
        _Pragma("unroll")                                                       \
        for (int i2 = 0; i2 < 4; ++i2) {                                        \
            int r  = rB + 128 * i1;                                             \
            int c4 = c4B + 4 * i2;                                              \
            int c  = c0 - RT + r;                                               \
            float4 v = make_float4(0.f, 0.f, 0.f, 0.f);                         \
            if (r < NCOLS && c >= 0 && c < C_)                                  \
                v = *(const float4*)(xb + (size_t)c * T_ + (T0) + c4 * 4);      \
            stg[i1][i2] = v;                                                    \
        }                                                                       \
    }

#define STAGE_WRITE()                                                           \
    _Pragma("unroll")                                                           \
    for (int i1 = 0; i1 < 2; ++i1) {                                            \
        _Pragma("unroll")                                                       \
        for (int i2 = 0; i2 < 4; ++i2) {                                        \
            int r  = rB + 128 * i1;                                             \
            int c4 = c4B + 4 * i2;                                              \
            if (r < NCOLS) {                                                    \
                xsT[(4 * c4 + 0) * XSTR + r] = stg[i1][i2].x;                   \
                xsT[(4 * c4 + 1) * XSTR + r] = stg[i1][i2].y;                   \
                xsT[(4 * c4 + 2) * XSTR + r] = stg[i1][i2].z;                   \
                xsT[(4 * c4 + 3) * XSTR + r] = stg[i1][i2].w;                   \
            }                                                                   \
        }                                                                       \
    }

    STAGE_LOAD(0);

    float mem = 0.0f;                       // channel c0+rb+tx (lanes tx<8)
    float rc  = 0.0f;                       // carried reset (= previous spike)
    float* strip = IsS + ty * (KC * ISTR);  // wave-local I strip

#pragma unroll 1
    for (int kk = 0; kk < T_ / TT; ++kk) {
        const int t0 = kk * TT;

        STAGE_WRITE();          // chunk kk -> xsT
        __syncthreads();        // xsT ready for all waves

        if (kk < T_ / TT - 1) { STAGE_LOAD(t0 + TT); }  // hides under conv

        // ---- conv: 48 x ds_read_b128 + 1536 reg-only FMA (taps in VGPRs) ----
        float acc[KC];
#pragma unroll
        for (int k = 0; k < KC; ++k) acc[k] = 0.0f;

        const float4* xrow4 = (const float4*)(&xsT[tx * XSTR + rb]);
#pragma unroll
        for (int jq = 0; jq < NJQ; ++jq) {      // fully unrolled: static tap idx
            float4 xv = xrow4[jq];
#pragma unroll
            for (int qq = 0; qq < 4; ++qq) {
                float x1 = EL(xv, qq);
#pragma unroll
                for (int k = 0; k < KC; ++k) {
                    const int idx = 4 * jq + qq + 7 - k;   // d = idx - 99
                    acc[k] = fmaf(EL(wq[idx >> 2], idx & 3), x1, acc[k]);
                }
            }
        }

        // I = x - conv -> wave-local strip (no cross-wave hazard)
        {
            float4 xoA = *(const float4*)((const float*)xrow4 + RT);
            float4 xoB = *(const float4*)((const float*)xrow4 + RT + 4);
            float xo[KC] = {xoA.x, xoA.y, xoA.z, xoA.w, xoB.x, xoB.y, xoB.z, xoB.w};
#pragma unroll
            for (int k = 0; k < KC; ++k)
                strip[k * ISTR + tx] = __fsub_rn(xo[k], acc[k]);
        }

        // ---- wave-local LIF scan (lanes tx<8; channel rb+tx) ----
        // reset = RN(soft + RN(1-soft)) == 1.0f exactly for soft in (0,0.5):
        // the atan surrogate is bit-exactly a compare; reset_{t+1} == spike_t.
        if (tx < KC) {
            float m = mem, r = rc;
            const float* srow = strip + tx * ISTR;
            float* orow = ob + (size_t)(c0 + rb + tx) * T_ + t0;
#pragma unroll 4
            for (int q = 0; q < TT / 4; ++q) {
                float4 Iq = *(const float4*)(srow + 4 * q);
                float4 s;
#pragma unroll
                for (int qq = 0; qq < 4; ++qq) {
                    float Ivv = EL(Iq, qq);
                    m = __fsub_rn(__fadd_rn(__fmul_rn(0.95f, m), Ivv), r);
                    float sp = (m > 1.0f) ? 1.0f : 0.0f;
                    r = sp;
                    if (qq == 0) s.x = sp; else if (qq == 1) s.y = sp;
                    else if (qq == 2) s.z = sp; else s.w = sp;
                }
                *(float4*)(orow + 4 * q) = s;
            }
            mem = m; rc = r;
        }
        __syncthreads();        // all xsT reads done before next STAGE_WRITE
    }
#undef STAGE_LOAD
#undef STAGE_WRITE
}

extern "C" void kernel_launch(void* const* d_in, const int* in_sizes, int n_in,
                              void* d_out, int out_size, void* d_ws, size_t ws_size,
                              hipStream_t stream) {
    const float* x     = (const float*)d_in[0];   // [32,1024,1024] f32
    const float* sigma = (const float*)d_in[1];   // [1] f32
    float* out = (float*)d_out;

    dim3 grid(C_ / CT, B_);   // (16, 32) = 512 blocks
    dim3 block(64, NTY);      // 512 threads, 8 waves

    if (ws_size >= NWT * sizeof(float)) {
        float* gw = (float*)d_ws;
        init_w_kernel<<<1, 256, 0, stream>>>(sigma, gw);
        snn_v8<true><<<grid, block, 0, stream>>>(x, sigma, gw, out);
    } else {
        snn_v8<false><<<grid, block, 0, stream>>>(x, sigma, nullptr, out);
    }
}

// Round 9
// 249.698 us; speedup vs baseline: 4.3870x; 4.3870x over previous
//
#include <hip/hip_runtime.h>
#include <math.h>

// B,C,T = 32,1024,1024; beta=0.95; thr=1.0; sigma=10.5
#define B_     32
#define C_     1024
#define T_     1024
#define RT     92                    // tap radius (|d|>92 cannot flip any f32 spike; validated r2-r8)
#define CT     64                    // channels per block
#define TT     64                    // time chunk
#define KC     8                     // channels per thread group
#define NTY    8                     // 8 waves, 512 threads
#define NJQ    48                    // 192 source cols / 4 per b128
#define WOFF   (RT + KC - 1)         // 99 center: tap idx = d + 99
#define NWT    200                   // tap floats (50 quads; idx 0..198 real)
#define NCOLS  (CT + 2*RT)           // 248 staged channel columns
#define XSTR   252                   // xsT row stride (dwords): 16B-aligned

// numpy-faithful f32 tap (identical op sequence; exp via correctly-rounded f64).
__device__ __forceinline__ float tap_value(float s, int d) {
    float u    = __fdiv_rn((float)d, s);
    float t1   = __fmul_rn(-0.5f, u);
    float t2   = __fmul_rn(t1, u);
    float e    = (float)exp((double)t2);
    float den  = __fmul_rn(s, sqrtf(6.2831854820251465f));
    float coef = __fdiv_rn(1.0f, den);
    return __fmul_rn(coef, e);
}

#define EL(v, i) ((i) == 0 ? (v).x : (i) == 1 ? (v).y : (i) == 2 ? (v).z : (v).w)

// xsT[t][chan_col] transposed tile -> conv reads ds_read_b128 along j.
// Taps in LDS, read as wave-uniform b128 broadcasts inside a fully-unrolled
// straight-line conv (no SMEM in the loop -> all loads on the in-order DS
// queue -> precise lgkmcnt(N), no drains).  I-strip is [t][k]-interleaved and
// wave-local.  Thread (tx,ty): channels c0+ty*8+k at t=t0+tx.
__global__ __launch_bounds__(512, 4) void snn_v9(
    const float* __restrict__ x, const float* __restrict__ sigma,
    float* __restrict__ out)
{
    __shared__ __align__(16) float xsT[TT * XSTR];       // 64512 B
    __shared__ __align__(16) float IsS[NTY * TT * KC];   // 16384 B ([t][k] per wave)
    __shared__ __align__(16) float wtab[NWT];            //   800 B  (total 81696)

    const int tx   = threadIdx.x;       // t lane 0..63
    const int ty   = threadIdx.y;       // wave 0..7
    const int flat = ty * 64 + tx;
    const int b    = blockIdx.y;
    const int c0   = blockIdx.x * CT;
    const int rb   = ty * KC;           // first local channel of this wave

    // ---- per-block tap table (bit-identical values to all passing rounds) ----
    if (flat < NWT) {
        int d = flat - WOFF;
        wtab[flat] = (d >= -RT && d <= RT) ? tap_value(sigma[0], d) : 0.0f;
    }

    const float* xb = x   + (size_t)b * ((size_t)C_ * T_);
    float*       ob = out + (size_t)b * ((size_t)C_ * T_);

    // ---- register staging (T14): (r = chan col, c4 = t-quad) ----
    float4 stg[2][4];                   // statically indexed only (rule #20)
    const int rB  = (flat >> 2);        // 0..127
    const int c4B = (flat & 3);         // 0..3

#define STAGE_LOAD(T0)                                                          \
    _Pragma("unroll")                                                           \
    for (int i1 = 0; i1 < 2; ++i1) {                                            \
        _Pragma("unroll")                                                       \
        for (int i2 = 0; i2 < 4; ++i2) {                                        \
            int r  = rB + 128 * i1;                                             \
            int c4 = c4B + 4 * i2;                                              \
            int c  = c0 - RT + r;                                               \
            float4 v = make_float4(0.f, 0.f, 0.f, 0.f);                         \
            if (r < NCOLS && c >= 0 && c < C_)                                  \
                v = *(const float4*)(xb + (size_t)c * T_ + (T0) + c4 * 4);      \
            stg[i1][i2] = v;                                                    \
        }                                                                       \
    }

#define STAGE_WRITE()                                                           \
    _Pragma("unroll")                                                           \
    for (int i1 = 0; i1 < 2; ++i1) {                                            \
        _Pragma("unroll")                                                       \
        for (int i2 = 0; i2 < 4; ++i2) {                                        \
            int r  = rB + 128 * i1;                                             \
            int c4 = c4B + 4 * i2;                                              \
            if (r < NCOLS) {                                                    \
                xsT[(4 * c4 + 0) * XSTR + r] = stg[i1][i2].x;                   \
                xsT[(4 * c4 + 1) * XSTR + r] = stg[i1][i2].y;                   \
                xsT[(4 * c4 + 2) * XSTR + r] = stg[i1][i2].z;                   \
                xsT[(4 * c4 + 3) * XSTR + r] = stg[i1][i2].w;                   \
            }                                                                   \
        }                                                                       \
    }

    STAGE_LOAD(0);

    float mem = 0.0f;                   // channel c0+rb+tx (lanes tx<8)
    float rc  = 0.0f;                   // carried reset (= previous spike)
    float* strip = IsS + ty * (TT * KC);          // wave-local [t][k] strip
    const float4* wt4 = (const float4*)wtab;

#pragma unroll 1
    for (int kk = 0; kk < T_ / TT; ++kk) {
        const int t0 = kk * TT;

        STAGE_WRITE();          // chunk kk -> xsT
        __syncthreads();        // xsT (and wtab on kk==0) ready for all waves

        if (kk < T_ / TT - 1) { STAGE_LOAD(t0 + TT); }  // hides under conv

        // ---- conv: fully-unrolled; ~50 uniform tap b128 + 48 x b128, all DS ----
        float acc[KC];
#pragma unroll
        for (int k = 0; k < KC; ++k) acc[k] = 0.0f;

        const float4* xr = (const float4*)(&xsT[tx * XSTR + rb]);
#pragma unroll
        for (int jq = 0; jq < NJQ; ++jq) {
            float4 xv = xr[jq];
            float4 wa = wt4[jq];        // GVN/CSE dedupes overlapping quads
            float4 wb = wt4[jq + 1];
            float4 wc = wt4[jq + 2];
#pragma unroll
            for (int qq = 0; qq < 4; ++qq) {
                float x1 = EL(xv, qq);
#pragma unroll
                for (int k = 0; k < KC; ++k) {
                    const int idx = qq + 7 - k;        // 0..10, compile-time
                    float wv = (idx < 4) ? EL(wa, idx)
                             : (idx < 8) ? EL(wb, idx - 4) : EL(wc, idx - 8);
                    acc[k] = fmaf(wv, x1, acc[k]);     // ascending j, exact chain
                }
            }
        }

        // I = x - conv -> wave-local strip[t][k] (2 contiguous b128 per thread)
        {
            float4 xoA = xr[RT / 4];        // dwords rb+92..95 (CSE with jq=23)
            float4 xoB = xr[RT / 4 + 1];    // dwords rb+96..99 (CSE with jq=24)
            float4 i0, i1;
            i0.x = __fsub_rn(xoA.x, acc[0]);
            i0.y = __fsub_rn(xoA.y, acc[1]);
            i0.z = __fsub_rn(xoA.z, acc[2]);
            i0.w = __fsub_rn(xoA.w, acc[3]);
            i1.x = __fsub_rn(xoB.x, acc[4]);
            i1.y = __fsub_rn(xoB.y, acc[5]);
            i1.z = __fsub_rn(xoB.z, acc[6]);
            i1.w = __fsub_rn(xoB.w, acc[7]);
            float4* srow = (float4*)(strip + tx * KC);
            srow[0] = i0;
            srow[1] = i1;
        }

        // ---- wave-local LIF scan (lanes tx<8; channel rb+tx) ----
        // reset = RN(soft + RN(1-soft)) == 1.0f exactly for soft in (0,0.5):
        // the atan surrogate is bit-exactly a compare; reset_{t+1} == spike_t.
        if (tx < KC) {
            float m = mem, r = rc;
            float* orow = ob + (size_t)(c0 + rb + tx) * T_ + t0;
#pragma unroll 4
            for (int q = 0; q < TT / 4; ++q) {
                float4 s;
#pragma unroll
                for (int qq = 0; qq < 4; ++qq) {
                    float Ivv = strip[(4 * q + qq) * KC + tx];  // bank 8t+k: conflict-free
                    m = __fsub_rn(__fadd_rn(__fmul_rn(0.95f, m), Ivv), r);
                    float sp = (m > 1.0f) ? 1.0f : 0.0f;
                    r = sp;
                    if (qq == 0) s.x = sp; else if (qq == 1) s.y = sp;
                    else if (qq == 2) s.z = sp; else s.w = sp;
                }
                *(float4*)(orow + 4 * q) = s;
            }
            mem = m; rc = r;
        }
        __syncthreads();        // all xsT reads done before next STAGE_WRITE
    }
#undef STAGE_LOAD
#undef STAGE_WRITE
}

extern "C" void kernel_launch(void* const* d_in, const int* in_sizes, int n_in,
                              void* d_out, int out_size, void* d_ws, size_t ws_size,
                              hipStream_t stream) {
    const float* x     = (const float*)d_in[0];   // [32,1024,1024] f32
    const float* sigma = (const float*)d_in[1];   // [1] f32
    float* out = (float*)d_out;

    dim3 grid(C_ / CT, B_);   // (16, 32) = 512 blocks, 2/CU
    dim3 block(64, NTY);      // 512 threads, 8 waves

    snn_v9<<<grid, block, 0, stream>>>(x, sigma, out);
}

// Round 11
// 183.457 us; speedup vs baseline: 5.9711x; 1.3611x over previous
//
#include <hip/hip_runtime.h>
#include <math.h>

// B,C,T = 32,1024,1024; beta=0.95; thr=1.0; sigma=10.5
#define B_     32
#define C_     1024
#define T_     1024
#define RT     92                    // tap radius (|d|>92 cannot flip any f32 spike; validated r2-r9)
#define CT     64                    // channels per block
#define TT     64                    // time chunk
#define KC     8                     // channels per thread group
#define NTY    8                     // 8 waves, 512 threads
#define WOFF   (RT + KC - 1)         // 99: tap idx = d + 99, idx in [0,198]
#define NWT    200                   // tap floats (50 quads, rows 0..49 pads)
#define NCOLS  (CT + 2*RT)           // 248 staged channel columns
#define XSTR   252                   // xsT row stride (dwords); cols 248..251 = tap pad
#define ISTR   65                    // I-strip row stride (dwords): conflict-free
#define NF4    (NCOLS * (TT/4))      // 3968 staged float4s per chunk

// numpy-faithful f32 tap (identical op sequence; exp via correctly-rounded f64).
__device__ __forceinline__ float tap_value(float s, int d) {
    float u    = __fdiv_rn((float)d, s);
    float t1   = __fmul_rn(-0.5f, u);
    float t2   = __fmul_rn(t1, u);
    float e    = (float)exp((double)t2);
    float den  = __fmul_rn(s, sqrtf(6.2831854820251465f));
    float coef = __fdiv_rn(1.0f, den);
    return __fmul_rn(coef, e);
}

#define EL(v, i) ((i) == 0 ? (v).x : (i) == 1 ? (v).y : (i) == 2 ? (v).z : (v).w)

// One j-quad conv step: 4 ascending-j source cols, 8 outputs each.
// rel tap idx = qq+7-k in [0,10] -> (WA,WB,WC) select, all compile-time.
#define FMASTEP(A, WA, WB, WC)                                                  \
    do {                                                                        \
        _Pragma("unroll")                                                       \
        for (int qq = 0; qq < 4; ++qq) {                                        \
            float x1 = EL(A, qq);                                               \
            _Pragma("unroll")                                                   \
            for (int k = 0; k < KC; ++k) {                                      \
                const int il = qq + 7 - k;                                      \
                float wv = (il < 4) ? EL(WA, il)                                \
                         : (il < 8) ? EL(WB, il - 4) : EL(WC, il - 8);          \
                acc[k] = fmaf(wv, x1, acc[k]);                                  \
            }                                                                   \
        }                                                                       \
    } while (0)

// xsT[t][chan_col] transposed tile (reg-staged, proven v6 path). Conv = 8
// passes; each preloads 8 tap quads (32 VGPR) from xsT row-pads into named
// registers and pipelines 6 x-b128 reads -> no tap fetch inside the FMA
// stream, pure in-order DS queue, no SMEM anywhere in the loop.
__global__ __launch_bounds__(512, 4) void snn_v11(
    const float* __restrict__ x, const float* __restrict__ sigma,
    float* __restrict__ out)
{
    __shared__ __align__(16) float xsT[TT * XSTR];       // 64512 B (incl. tap pads)
    __shared__ __align__(16) float IsS[NTY * KC * ISTR]; // 16640 B (total 81152)

    const int tx   = threadIdx.x;      // t lane 0..63
    const int ty   = threadIdx.y;      // wave 0..7
    const int flat = ty * 64 + tx;
    const int b    = blockIdx.y;
    const int c0   = blockIdx.x * CT;
    const int rb   = ty * KC;

    const float* xb = x   + (size_t)b * ((size_t)C_ * T_);
    float*       ob = out + (size_t)b * ((size_t)C_ * T_);

    // ---- taps into xsT row pads (rows 0..49, cols 248..251) ----
    if (flat < NWT) {
        int d = flat - WOFF;
        xsT[(flat >> 2) * XSTR + 248 + (flat & 3)] =
            (d >= -RT && d <= RT) ? tap_value(sigma[0], d) : 0.0f;
    }

    // ---- register staging (proven v6 path): (r = chan col, c4 = t-quad) ----
    float4 stg[2][4];                  // statically indexed only (rule #20)
    const int rB  = (flat >> 2);       // 0..127
    const int c4B = (flat & 3);        // 0..3

#define STAGE_LOAD(T0)                                                          \
    _Pragma("unroll")                                                           \
    for (int i1 = 0; i1 < 2; ++i1) {                                            \
        _Pragma("unroll")                                                       \
        for (int i2 = 0; i2 < 4; ++i2) {                                        \
            int r  = rB + 128 * i1;                                             \
            int c4 = c4B + 4 * i2;                                              \
            int c  = c0 - RT + r;                                               \
            float4 v = make_float4(0.f, 0.f, 0.f, 0.f);                         \
            if (r < NCOLS && c >= 0 && c < C_)                                  \
                v = *(const float4*)(xb + (size_t)c * T_ + (T0) + c4 * 4);      \
            stg[i1][i2] = v;                                                    \
        }                                                                       \
    }

#define STAGE_WRITE()                                                           \
    _Pragma("unroll")                                                           \
    for (int i1 = 0; i1 < 2; ++i1) {                                            \
        _Pragma("unroll")                                                       \
        for (int i2 = 0; i2 < 4; ++i2) {                                        \
            int r  = rB + 128 * i1;                                             \
            int c4 = c4B + 4 * i2;                                              \
            if (r < NCOLS) {                                                    \
                xsT[(4 * c4 + 0) * XSTR + r] = stg[i1][i2].x;                   \
                xsT[(4 * c4 + 1) * XSTR + r] = stg[i1][i2].y;                   \
                xsT[(4 * c4 + 2) * XSTR + r] = stg[i1][i2].z;                   \
                xsT[(4 * c4 + 3) * XSTR + r] = stg[i1][i2].w;                   \
            }                                                                   \
        }                                                                       \
    }

#define TAPQ(Q) (*(const float4*)(xsT + (Q) * XSTR + 248))

    // Pass P: j-quads 6P..6P+5 (ascending), tap quads 6P..6P+7 in registers.
#define PASS(P)                                                                 \
    do {                                                                        \
        float4 w0 = TAPQ(6*(P)+0), w1 = TAPQ(6*(P)+1), w2 = TAPQ(6*(P)+2);      \
        float4 w3 = TAPQ(6*(P)+3), w4 = TAPQ(6*(P)+4), w5 = TAPQ(6*(P)+5);      \
        float4 w6 = TAPQ(6*(P)+6), w7 = TAPQ(6*(P)+7);                          \
        float4 a0 = xq[6*(P)+0], a1 = xq[6*(P)+1], a2 = xq[6*(P)+2];            \
        float4 a3 = xq[6*(P)+3], a4 = xq[6*(P)+4], a5 = xq[6*(P)+5];            \
        FMASTEP(a0, w0, w1, w2);                                                \
        FMASTEP(a1, w1, w2, w3);                                                \
        FMASTEP(a2, w2, w3, w4);                                                \
        FMASTEP(a3, w3, w4, w5);                                                \
        FMASTEP(a4, w4, w5, w6);                                                \
        FMASTEP(a5, w5, w6, w7);                                                \
    } while (0)

    STAGE_LOAD(0);

    float mem = 0.0f;                  // channel c0+rb+tx (lanes tx<8)
    float rc  = 0.0f;                  // carried reset (= previous spike)
    float* strip = IsS + ty * (KC * ISTR);
    const float4* xq = (const float4*)(xsT + tx * XSTR + rb);

#pragma unroll 1
    for (int kk = 0; kk < T_ / TT; ++kk) {
        STAGE_WRITE();          // chunk kk -> xsT (waits its own vmcnt)
        __syncthreads();        // xsT + taps ready for all waves

        if (kk < T_ / TT - 1) { STAGE_LOAD((kk + 1) * TT); }  // hides under conv

        // ---- conv: 8 passes, taps resident in VGPRs, 48 x-b128 reads ----
        float acc[KC];
#pragma unroll
        for (int k = 0; k < KC; ++k) acc[k] = 0.0f;

        PASS(0); PASS(1); PASS(2); PASS(3);
        PASS(4); PASS(5); PASS(6); PASS(7);     // ascending j, exact f32 chain

        // I = x - conv -> wave-local strip
        {
            float4 xo0 = xq[RT / 4];        // own x, dwords rb+92..95
            float4 xo1 = xq[RT / 4 + 1];    // rb+96..99
            strip[0 * ISTR + tx] = __fsub_rn(xo0.x, acc[0]);
            strip[1 * ISTR + tx] = __fsub_rn(xo0.y, acc[1]);
            strip[2 * ISTR + tx] = __fsub_rn(xo0.z, acc[2]);
            strip[3 * ISTR + tx] = __fsub_rn(xo0.w, acc[3]);
            strip[4 * ISTR + tx] = __fsub_rn(xo1.x, acc[4]);
            strip[5 * ISTR + tx] = __fsub_rn(xo1.y, acc[5]);
            strip[6 * ISTR + tx] = __fsub_rn(xo1.z, acc[6]);
            strip[7 * ISTR + tx] = __fsub_rn(xo1.w, acc[7]);
        }
        __syncthreads();        // all xsT reads done; strips visible

        // ---- wave-local LIF scan (lanes tx<8; channel c0+rb+tx) ----
        // reset = RN(soft + RN(1-soft)) == 1.0f exactly for soft in (0,0.5):
        // the atan surrogate is bit-exactly a compare; reset_{t+1} == spike_t.
        if (tx < KC) {
            float m = mem, r = rc;
            const float* srow = strip + tx * ISTR;
            float* orow = ob + (size_t)(c0 + rb + tx) * T_ + (size_t)kk * TT;
#pragma unroll 4
            for (int q = 0; q < TT / 4; ++q) {
                float4 s;
#pragma unroll
                for (int qq = 0; qq < 4; ++qq) {
                    float Ivv = srow[4 * q + qq];
                    m = __fsub_rn(__fadd_rn(__fmul_rn(0.95f, m), Ivv), r);
                    float sp = (m > 1.0f) ? 1.0f : 0.0f;
                    r = sp;
                    if (qq == 0) s.x = sp; else if (qq == 1) s.y = sp;
                    else if (qq == 2) s.z = sp; else s.w = sp;
                }
                *(float4*)(orow + 4 * q) = s;
            }
            mem = m; rc = r;
        }
        // no barrier needed here: scan reads own wave's strip; next iter's
        // STAGE_WRITE touches only xsT, whose reads completed pre-barrier...
        __syncthreads();        // ...but strip[k]: next I-write is same-wave; keep
                                // one barrier for xsT WAR safety across waves
    }
#undef STAGE_LOAD
#undef STAGE_WRITE
#undef TAPQ
#undef PASS
}

extern "C" void kernel_launch(void* const* d_in, const int* in_sizes, int n_in,
                              void* d_out, int out_size, void* d_ws, size_t ws_size,
                              hipStream_t stream) {
    const float* x     = (const float*)d_in[0];   // [32,1024,1024] f32
    const float* sigma = (const float*)d_in[1];   // [1] f32
    float* out = (float*)d_out;

    dim3 grid(C_ / CT, B_);   // (16, 32) = 512 blocks, 2/CU
    dim3 block(64, NTY);      // 512 threads, 8 waves

    snn_v11<<<grid, block, 0, stream>>>(x, sigma, out);
}